// Round 22
// baseline (179.255 us; speedup 1.0000x reference)
//
#include <hip/hip_runtime.h>
#include <math.h>

#define N_NODES 50000
#define N_EDGES 800000
#define N_GRAPHS 64
#define NEG_SLOPE 0.2f
#define N_REP 64   // pooled-sum replicas (contention breaker)
#define ZERO_INT4 ((N_NODES * 4 + N_REP * N_GRAPHS * 64 * 4) / 16)
#define FILL_GRID 2048
#define NPX (N_NODES / 8)   // 6250 nodes per xcd-range
#define SLOT 64             // fixed CSR slots per node (max degree 12 sigma out)
#define O1LD 264            // padded LDS row (ushorts) for the 16x256 tile

typedef __attribute__((ext_vector_type(8))) short short8;
typedef __attribute__((ext_vector_type(4))) float f32x4;

__device__ __forceinline__ float lrelu(float x) { return x > 0.f ? x : NEG_SLOPE * x; }

__device__ __forceinline__ unsigned short f2bf(float f) {
    union { float f; unsigned int u; } v; v.f = f;
    unsigned int r = (v.u + 0x7fffu + ((v.u >> 16) & 1u)) >> 16;  // RNE
    return (unsigned short)r;
}
__device__ __forceinline__ float bf2f(unsigned short b) {
    union { unsigned int u; float f; } v; v.u = ((unsigned int)b) << 16;
    return v.f;
}
__device__ __forceinline__ float bfLO(unsigned int u) {
    union { unsigned int u; float f; } v; v.u = u << 16;
    return v.f;
}
__device__ __forceinline__ float bfHI(unsigned int u) {
    union { unsigned int u; float f; } v; v.u = u & 0xffff0000u;
    return v.f;
}

__device__ __forceinline__ int lower_bound_i(const int* __restrict__ a, int n, int v) {
    int lo = 0, hi = n;
    while (lo < hi) { int m = (lo + hi) >> 1; if (a[m] < v) lo = m + 1; else hi = m; }
    return lo;
}

// ---------------- Layer 1 logits + prep (zero, xpad, W2 permute) ----------------
__global__ __launch_bounds__(256) void k_gemm1(const float* __restrict__ x,
                                               const float* __restrict__ W1,
                                               const float* __restrict__ att_s,
                                               const float* __restrict__ att_d,
                                               const float* __restrict__ W2,
                                               float4* __restrict__ a_s,
                                               float4* __restrict__ a_d,
                                               int4* __restrict__ zp,
                                               float4* __restrict__ xp4,
                                               unsigned short* __restrict__ lWg) {
    __shared__ float Ws[5 * 256];
    const int t = threadIdx.x;
    {   // fused zero of counts+sums
        int tid = blockIdx.x * 256 + t;
        if (tid < ZERO_INT4) zp[tid] = make_int4(0, 0, 0, 0);
    }
    if (blockIdx.x < 64) {   // fused W2 permute to bf16 [s][g][tt][c16][j]
        int idx = blockIdx.x * 256 + t;
        int j = idx & 7, c16 = (idx >> 3) & 15, tt = (idx >> 7) & 3,
            g = (idx >> 9) & 3, s = idx >> 11;
        int k = 32 * s + 8 * g + j, c = 16 * tt + c16;
        lWg[idx] = f2bf(W2[k * 64 + c]);
    }
    for (int i = t; i < 5 * 256; i += 256) Ws[i] = W1[i];
    __syncthreads();
    const int wave = t >> 6, lane = t & 63;
    const int n = blockIdx.x * 4 + wave;
    if (n >= N_NODES) return;
    float x0 = x[n * 5 + 0], x1 = x[n * 5 + 1], x2 = x[n * 5 + 2],
          x3 = x[n * 5 + 3], x4 = x[n * 5 + 4];
    if (lane == 0) {   // fused xpad
        xp4[n * 2]     = make_float4(x0, x1, x2, x3);
        xp4[n * 2 + 1] = make_float4(x4, 0.f, 0.f, 0.f);
    }
    float vs[4], vd[4];
#pragma unroll
    for (int hd = 0; hd < 4; ++hd) {
        const int c = hd * 64 + lane;
        float h = x0 * Ws[c] + x1 * Ws[256 + c] + x2 * Ws[512 + c] +
                  x3 * Ws[768 + c] + x4 * Ws[1024 + c];
        vs[hd] = h * att_s[c];
        vd[hd] = h * att_d[c];
    }
#pragma unroll
    for (int off = 32; off; off >>= 1) {
#pragma unroll
        for (int hd = 0; hd < 4; ++hd) {
            vs[hd] += __shfl_xor(vs[hd], off, 64);
            vd[hd] += __shfl_xor(vd[hd], off, 64);
        }
    }
    if (lane == 0) {
        a_s[n] = make_float4(vs[0], vs[1], vs[2], vs[3]);
        a_d[n] = make_float4(vd[0], vd[1], vd[2], vd[3]);
    }
}

// ---------------- CSR build: ONE fused pass (XCD-tiled count + slot scatter) -
__global__ __launch_bounds__(256) void k_fill2(const int* __restrict__ src,
                                               const int* __restrict__ dst,
                                               int* __restrict__ cnt,
                                               int* __restrict__ csr_src) {
    const int r = blockIdx.x & 7;
    const int slice = blockIdx.x >> 3;                  // 0..255
    const int lo = r * NPX;
    const int per = (N_EDGES + (FILL_GRID / 8) - 1) / (FILL_GRID / 8);  // 3125
    const int e0 = slice * per;
    const int e1 = min(e0 + per, N_EDGES);
    for (int e = e0 + threadIdx.x; e < e1; e += 256) {
        int d = dst[e];
        if ((unsigned)(d - lo) < (unsigned)NPX) {
            int rk = atomicAdd(&cnt[d], 1);
            if (rk < SLOT) csr_src[(d << 6) + rk] = src[e];
        }
    }
}

// ---------------- FUSED layer-1 aggregation + layer-2 MFMA GEMM --------------
__global__ __launch_bounds__(256) void k_fuse(const float4* __restrict__ xp4,
                                              const float* __restrict__ W1,
                                              const float4* __restrict__ asv,
                                              const float4* __restrict__ adv,
                                              const int* __restrict__ cnt,
                                              const int* __restrict__ csr_src,
                                              const float* __restrict__ b1,
                                              const unsigned short* __restrict__ lWg,
                                              const float* __restrict__ att_s2,
                                              const float* __restrict__ att_d2,
                                              unsigned short* __restrict__ h2b,
                                              float* __restrict__ a_s2,
                                              float* __restrict__ a_d2) {
    __shared__ unsigned short o1[16][O1LD];   // 8448 B
    __shared__ float hand[4][4][24];
    __shared__ float vsp[4][16][2];
    const int t = threadIdx.x;
    const int wave = t >> 6, lane = t & 63;
    const int grp = lane >> 4, l16 = lane & 15;
    const int nb = blockIdx.x * 16;
    const int d = nb + wave * 4 + grp;

    // ---- Phase A: layer-1 aggregation (sum-swapped) ----
    float w1r[4][5], bias[4];
#pragma unroll
    for (int h = 0; h < 4; ++h) {
#pragma unroll
        for (int i = 0; i < 5; ++i) w1r[h][i] = W1[i * 256 + h * 64 + lane];
        bias[h] = b1[h * 64 + lane];
    }

    const int beg = d << 6;
    const int end = beg + min(cnt[d], SLOT);
    const float4 ad = adv[d];

    float den[4] = {0.f, 0.f, 0.f, 0.f};
    float xw[4][5];
#pragma unroll
    for (int h = 0; h < 4; ++h)
#pragma unroll
        for (int i = 0; i < 5; ++i) xw[h][i] = 0.f;

    for (int cb = beg; cb < end; cb += 16) {
        const int j = cb + l16;
        if (j < end) {
            const int s = csr_src[j];
            const float4 a = asv[s];
            float w[4];
            w[0] = __expf(lrelu(a.x + ad.x));
            w[1] = __expf(lrelu(a.y + ad.y));
            w[2] = __expf(lrelu(a.z + ad.z));
            w[3] = __expf(lrelu(a.w + ad.w));
            float4 xa = xp4[2 * s];
            float4 xb = xp4[2 * s + 1];
            float xv[5] = {xa.x, xa.y, xa.z, xa.w, xb.x};
#pragma unroll
            for (int h = 0; h < 4; ++h) {
                den[h] += w[h];
#pragma unroll
                for (int i = 0; i < 5; ++i) xw[h][i] += w[h] * xv[i];
            }
        }
    }

#pragma unroll
    for (int off = 1; off < 16; off <<= 1) {
#pragma unroll
        for (int h = 0; h < 4; ++h) {
            den[h] += __shfl_xor(den[h], off, 64);
#pragma unroll
            for (int i = 0; i < 5; ++i) xw[h][i] += __shfl_xor(xw[h][i], off, 64);
        }
    }

    {   // self loop
        const float4 as = asv[d];
        float w[4];
        w[0] = __expf(lrelu(as.x + ad.x));
        w[1] = __expf(lrelu(as.y + ad.y));
        w[2] = __expf(lrelu(as.z + ad.z));
        w[3] = __expf(lrelu(as.w + ad.w));
        float4 xa = xp4[2 * d];
        float4 xb = xp4[2 * d + 1];
        float xv[5] = {xa.x, xa.y, xa.z, xa.w, xb.x};
#pragma unroll
        for (int h = 0; h < 4; ++h) {
            den[h] += w[h];
#pragma unroll
            for (int i = 0; i < 5; ++i) xw[h][i] += w[h] * xv[i];
        }
    }

    if (l16 == 0) {
#pragma unroll
        for (int h = 0; h < 4; ++h) hand[wave][grp][h] = den[h];
#pragma unroll
        for (int h = 0; h < 4; ++h)
#pragma unroll
            for (int i = 0; i < 5; ++i) hand[wave][grp][4 + h * 5 + i] = xw[h][i];
    }
    __syncthreads();

#pragma unroll
    for (int n = 0; n < 4; ++n) {
        const int nl = wave * 4 + n;   // local node 0..15
#pragma unroll
        for (int h = 0; h < 4; ++h) {
            const float dh = hand[wave][n][h] + 1e-16f;
            float hh = hand[wave][n][4 + h * 5 + 0] * w1r[h][0]
                     + hand[wave][n][4 + h * 5 + 1] * w1r[h][1]
                     + hand[wave][n][4 + h * 5 + 2] * w1r[h][2]
                     + hand[wave][n][4 + h * 5 + 3] * w1r[h][3]
                     + hand[wave][n][4 + h * 5 + 4] * w1r[h][4];
            o1[nl][h * 64 + lane] = f2bf(fmaxf(hh / dh + bias[h], 0.f));
        }
    }
    __syncthreads();

    // ---- Phase B: MFMA for this 16-node tile; wave = output channel slice ----
    const int tt = wave;
    const int g = lane >> 4, c16 = lane & 15;
    f32x4 acc = (f32x4){0.f, 0.f, 0.f, 0.f};
#pragma unroll
    for (int s = 0; s < 8; ++s) {
        short8 a = *reinterpret_cast<const short8*>(&o1[c16][32 * s + 8 * g]);
        short8 b = *reinterpret_cast<const short8*>(
            lWg + ((((s * 4 + g) * 4 + tt) * 16 + c16) << 3));
        acc = __builtin_amdgcn_mfma_f32_16x16x32_bf16(a, b, acc, 0, 0, 0);
    }

    const float attS = att_s2[16 * tt + c16];
    const float attD = att_d2[16 * tt + c16];
#pragma unroll
    for (int r = 0; r < 4; ++r) {
        const int node = nb + g * 4 + r;
        float v = acc[r];
        h2b[(size_t)node * 64 + 16 * tt + c16] = f2bf(v);
        float vs = v * attS, vd = v * attD;
#pragma unroll
        for (int off = 1; off < 16; off <<= 1) {
            vs += __shfl_xor(vs, off, 64);
            vd += __shfl_xor(vd, off, 64);
        }
        if (c16 == 0) {
            vsp[tt][g * 4 + r][0] = vs;
            vsp[tt][g * 4 + r][1] = vd;
        }
    }
    __syncthreads();
    if (t < 16) {
        float vs = vsp[0][t][0] + vsp[1][t][0] + vsp[2][t][0] + vsp[3][t][0];
        float vd = vsp[0][t][1] + vsp[1][t][1] + vsp[2][t][1] + vsp[3][t][1];
        a_s2[nb + t] = vs;
        a_d2[nb + t] = vd;
    }
}

// ---------------- Layer 2 aggregation + fused pool (v4, 8-deep ILP) ----------
__global__ __launch_bounds__(256) void k_agg2(const unsigned int* __restrict__ h2u,
                                              const float* __restrict__ as_,
                                              const float* __restrict__ ad_,
                                              const int* __restrict__ cnt,
                                              const int* __restrict__ csr_src,
                                              const float* __restrict__ b2,
                                              const int* __restrict__ batch,
                                              float* __restrict__ sums) {
    __shared__ int2 ew[4][2][32];
    const int t = threadIdx.x;
    const int wid = t >> 6, lane = t & 63;
    const int g = lane >> 5, m = lane & 31;
    const int d = blockIdx.x * 8 + wid * 2 + g;   // exact cover (50000/8=6250)
    const int bat_d = batch[d];                   // hoisted off epilogue path
    const int beg = d << 6;
    const int end = beg + min(cnt[d], SLOT);
    const float adl = ad_[d];

    float den = 0.f, accx = 0.f, accy = 0.f;
    for (int c = beg; c < end; c += 32) {
        int rem = end - c; if (rem > 32) rem = 32;
        if (m < rem) {
            int s = csr_src[c + m];
            float w = __expf(lrelu(as_[s] + adl));
            den += w;
            ew[wid][g][m] = make_int2(s, __float_as_int(w));
        }
        int e = 0;
        for (; e + 8 <= rem; e += 8) {   // 8 row-fetches in flight
            int2 p0 = ew[wid][g][e],     p1 = ew[wid][g][e + 1];
            int2 p2 = ew[wid][g][e + 2], p3 = ew[wid][g][e + 3];
            int2 p4 = ew[wid][g][e + 4], p5 = ew[wid][g][e + 5];
            int2 p6 = ew[wid][g][e + 6], p7 = ew[wid][g][e + 7];
            unsigned int v0 = h2u[(size_t)p0.x * 32 + m];
            unsigned int v1 = h2u[(size_t)p1.x * 32 + m];
            unsigned int v2 = h2u[(size_t)p2.x * 32 + m];
            unsigned int v3 = h2u[(size_t)p3.x * 32 + m];
            unsigned int v4 = h2u[(size_t)p4.x * 32 + m];
            unsigned int v5 = h2u[(size_t)p5.x * 32 + m];
            unsigned int v6 = h2u[(size_t)p6.x * 32 + m];
            unsigned int v7 = h2u[(size_t)p7.x * 32 + m];
            float w0 = __int_as_float(p0.y), w1 = __int_as_float(p1.y);
            float w2 = __int_as_float(p2.y), w3 = __int_as_float(p3.y);
            float w4 = __int_as_float(p4.y), w5 = __int_as_float(p5.y);
            float w6 = __int_as_float(p6.y), w7 = __int_as_float(p7.y);
            accx += w0 * bfLO(v0); accy += w0 * bfHI(v0);
            accx += w1 * bfLO(v1); accy += w1 * bfHI(v1);
            accx += w2 * bfLO(v2); accy += w2 * bfHI(v2);
            accx += w3 * bfLO(v3); accy += w3 * bfHI(v3);
            accx += w4 * bfLO(v4); accy += w4 * bfHI(v4);
            accx += w5 * bfLO(v5); accy += w5 * bfHI(v5);
            accx += w6 * bfLO(v6); accy += w6 * bfHI(v6);
            accx += w7 * bfLO(v7); accy += w7 * bfHI(v7);
        }
        for (; e + 4 <= rem; e += 4) {
            int2 p0 = ew[wid][g][e],     p1 = ew[wid][g][e + 1];
            int2 p2 = ew[wid][g][e + 2], p3 = ew[wid][g][e + 3];
            unsigned int v0 = h2u[(size_t)p0.x * 32 + m];
            unsigned int v1 = h2u[(size_t)p1.x * 32 + m];
            unsigned int v2 = h2u[(size_t)p2.x * 32 + m];
            unsigned int v3 = h2u[(size_t)p3.x * 32 + m];
            float w0 = __int_as_float(p0.y), w1 = __int_as_float(p1.y);
            float w2 = __int_as_float(p2.y), w3 = __int_as_float(p3.y);
            accx += w0 * bfLO(v0); accy += w0 * bfHI(v0);
            accx += w1 * bfLO(v1); accy += w1 * bfHI(v1);
            accx += w2 * bfLO(v2); accy += w2 * bfHI(v2);
            accx += w3 * bfLO(v3); accy += w3 * bfHI(v3);
        }
        for (; e < rem; ++e) {
            int2 p = ew[wid][g][e];
            unsigned int v = h2u[(size_t)p.x * 32 + m];
            float w = __int_as_float(p.y);
            accx += w * bfLO(v); accy += w * bfHI(v);
        }
    }
#pragma unroll
    for (int off = 16; off; off >>= 1) den += __shfl_xor(den, off, 64);  // in-group
    {   // self loop (uniform per group)
        float w = __expf(lrelu(as_[d] + adl));
        den += w;
        unsigned int v = h2u[(size_t)d * 32 + m];
        accx += w * bfLO(v); accy += w * bfHI(v);
    }
    float inv = 1.0f / (den + 1e-16f);
    float v0 = fmaxf(accx * inv + b2[2 * m], 0.f);
    float v1 = fmaxf(accy * inv + b2[2 * m + 1], 0.f);
    const int rep = ((blockIdx.x << 3) + (wid << 1) + g) & (N_REP - 1);
    float* sb = sums + (size_t)rep * (N_GRAPHS * 64) + bat_d * 64;
    atomicAdd(&sb[2 * m], v0);
    atomicAdd(&sb[2 * m + 1], v1);
}

// ---------------- Final: reduce replicas + mean + 64->2 linear ----------------
__global__ __launch_bounds__(64) void k_final(const float* __restrict__ sums,
                                              const int* __restrict__ batch,
                                              const float* __restrict__ linW,
                                              const float* __restrict__ linb,
                                              float* __restrict__ out) {
    const int g = blockIdx.x;
    const int lane = threadIdx.x;
    float s = 0.f;
#pragma unroll 8
    for (int r = 0; r < N_REP; ++r)
        s += sums[(size_t)r * (N_GRAPHS * 64) + g * 64 + lane];
    int beg = lower_bound_i(batch, N_NODES, g);
    int end = lower_bound_i(batch, N_NODES, g + 1);
    float val = s / fmaxf((float)(end - beg), 1.0f);
    float v0 = val * linW[lane * 2 + 0];
    float v1 = val * linW[lane * 2 + 1];
#pragma unroll
    for (int off = 32; off; off >>= 1) {
        v0 += __shfl_xor(v0, off, 64);
        v1 += __shfl_xor(v1, off, 64);
    }
    if (lane == 0) {
        out[g * 2 + 0] = v0 + linb[0];
        out[g * 2 + 1] = v1 + linb[1];
    }
}

extern "C" void kernel_launch(void* const* d_in, const int* in_sizes, int n_in,
                              void* d_out, int out_size, void* d_ws, size_t ws_size,
                              hipStream_t stream) {
    const float* x    = (const float*)d_in[0];
    const int*   ei   = (const int*)d_in[1];
    const int*   bat  = (const int*)d_in[2];
    const float* W1   = (const float*)d_in[3];
    const float* as1  = (const float*)d_in[4];
    const float* ad1  = (const float*)d_in[5];
    const float* b1   = (const float*)d_in[6];
    const float* W2   = (const float*)d_in[7];
    const float* as2  = (const float*)d_in[8];
    const float* ad2  = (const float*)d_in[9];
    const float* b2   = (const float*)d_in[10];
    const float* linW = (const float*)d_in[11];
    const float* linb = (const float*)d_in[12];
    float* out = (float*)d_out;

    const int* src = ei;
    const int* dst = ei + N_EDGES;

    char* w = (char*)d_ws;
    float4* a_s1 = (float4*)w; w += (size_t)N_NODES * 16;
    float4* a_d1 = (float4*)w; w += (size_t)N_NODES * 16;
    unsigned short* h2b = (unsigned short*)w; w += (size_t)N_NODES * 64 * 2;
    float* a_s2  = (float*)w; w += (size_t)N_NODES * 4;
    float* a_d2  = (float*)w; w += (size_t)N_NODES * 4;
    // counts + sums adjacent: ONE zero pass covers both
    int* counts  = (int*)w;   w += (size_t)N_NODES * 4;
    float* sums  = (float*)w; w += (size_t)N_REP * N_GRAPHS * 64 * 4;
    int* csr_src = (int*)w;   w += (size_t)N_NODES * SLOT * 4;   // 12.8 MB slots
    float4* xp4  = (float4*)w; w += (size_t)N_NODES * 32;
    unsigned short* lWg = (unsigned short*)w; w += 16384 * 2;

    // Layer 1 logits + prep (zero counts/sums, xpad, W2 permute)
    k_gemm1<<<(N_NODES + 3) / 4, 256, 0, stream>>>(x, W1, as1, ad1, W2, a_s1, a_d1,
                                                   (int4*)counts, xp4, lWg);
    // CSR build: ONE fused XCD-tiled pass (atomic rank + slot store)
    k_fill2<<<FILL_GRID, 256, 0, stream>>>(src, dst, counts, csr_src);

    // FUSED layer-1 aggregation + layer-2 GEMM
    k_fuse<<<N_NODES / 16, 256, 0, stream>>>(xp4, W1, a_s1, a_d1, counts, csr_src,
                                             b1, lWg, as2, ad2, h2b, a_s2, a_d2);
    // Layer 2 aggregation + pool
    k_agg2<<<N_NODES / 8, 256, 0, stream>>>((const unsigned int*)h2b, a_s2, a_d2,
                                            counts, csr_src, b2, bat, sums);
    // Reduce replicas + mean + linear
    k_final<<<N_GRAPHS, 64, 0, stream>>>(sums, bat, linW, linb, out);
}